// Round 1
// 213.818 us; speedup vs baseline: 1.0057x; 1.0057x over previous
//
#include <hip/hip_runtime.h>
#include <hip/hip_bf16.h>

#define H 1024
#define BATCH 16384

typedef unsigned short u16;
typedef u16 u16x8 __attribute__((ext_vector_type(8)));
typedef __bf16 bf16x8 __attribute__((ext_vector_type(8)));
typedef float f32x4 __attribute__((ext_vector_type(4)));

typedef __attribute__((address_space(3))) unsigned int lds_uint;
typedef __attribute__((address_space(1))) const unsigned int glob_uint;

__device__ __forceinline__ u16 f2bf(float f) {
  unsigned int u = __float_as_uint(f);
  u += 0x7fffu + ((u >> 16) & 1u);   // round-to-nearest-even
  return (u16)(u >> 16);
}

// ================= FAST PATH =================
// ws float offsets
#define WS_XSUMP   0                      // [256][1024] per-block col-sum partials
#define WS_XSUM    (WS_XSUMP + 256 * H)   // [1024] reduced col sums
#define WS_ORAWP   (WS_XSUM + H)          // [16][1024] vecmat partials (pre-scaled 1/B)
#define WS_POSVP   (WS_ORAWP + 16 * H)    // [5][1024]
#define WS_NEGHP   (WS_POSVP + 5 * H)     // [5][1024]
#define WS_SCRATCH (WS_NEGHP + 5 * H)     // unused spare
#define WS_BF16    (WS_SCRATCH + 16)      // Xb then Wbt (u16), 16B-aligned

// ---- K1: prep = convx (blocks 0..255) + convw (256..511) + stdp partials (512..531)
__global__ __launch_bounds__(256) void prep_kernel(const float* __restrict__ X,
                                                   const float* __restrict__ W,
                                                   u16* __restrict__ Xb,
                                                   u16* __restrict__ Wbt,
                                                   float* __restrict__ ws,
                                                   const float* __restrict__ pre,
                                                   const float* __restrict__ post,
                                                   const float* __restrict__ win,
                                                   const float* __restrict__ dec) {
  __shared__ __align__(16) u16 t[64][72];
  const int b = blockIdx.x, tid = threadIdx.x;
  if (b < 256) {
    // --- convert X fp32->bf16, per-block column partial sums (no atomics) ---
    size_t r0 = (size_t)b * 64;
    float s0 = 0.f, s1 = 0.f, s2 = 0.f, s3 = 0.f;
#pragma unroll 4
    for (int r = 0; r < 64; ++r) {
      size_t off = (r0 + r) * H + tid * 4;
      const float4 v = *(const float4*)&X[off];
      ushort4 h;
      h.x = f2bf(v.x); h.y = f2bf(v.y); h.z = f2bf(v.z); h.w = f2bf(v.w);
      *(ushort4*)&Xb[off] = h;
      s0 += v.x; s1 += v.y; s2 += v.z; s3 += v.w;
    }
    float* row = &ws[WS_XSUMP + b * H];
    row[tid * 4 + 0] = s0; row[tid * 4 + 1] = s1;
    row[tid * 4 + 2] = s2; row[tid * 4 + 3] = s3;
  } else if (b < 512) {
    // --- convert + transpose W -> Wbt bf16 [n][k] ---
    const int b2 = b - 256;
    const int n0 = (b2 & 15) * 64, k0 = (b2 >> 4) * 64;
    const int rb = tid >> 4, c4 = tid & 15;
#pragma unroll
    for (int i = 0; i < 4; ++i) {
      int r = rb + i * 16;
      const float4 v = *(const float4*)&W[(size_t)(k0 + r) * H + n0 + c4 * 4];
      t[c4 * 4 + 0][r] = f2bf(v.x);
      t[c4 * 4 + 1][r] = f2bf(v.y);
      t[c4 * 4 + 2][r] = f2bf(v.z);
      t[c4 * 4 + 3][r] = f2bf(v.w);
    }
    __syncthreads();
    const int seg = tid & 7;
#pragma unroll
    for (int p = 0; p < 2; ++p) {
      int wr = p * 32 + (tid >> 3);
      *(u16x8*)&Wbt[(size_t)(n0 + wr) * H + k0 + seg * 8] = *(const u16x8*)&t[wr][seg * 8];
    }
  } else {
    // --- STDP weighted history partials (no atomics) ---
    const int b2 = b - 512;               // 0..19
    const int col = (b2 & 3) * 256 + tid;
    const int seg = b2 >> 2;              // 0..4
    const int t0 = 1 + seg * 20;
    int tend = t0 + 20; if (tend > 100) tend = 100;
    float wd = win[0] * dec[0];
    float ps = 0.f, ns = 0.f;
    for (int tt = t0; tt < tend; ++tt) {
      float w = 0.01f * expf(-(float)(101 - tt) * wd);
      ps += w * pre[tt * H + col];
      if (tt >= 2) ns += w * post[tt * H + col];
    }
    ws[WS_POSVP + seg * H + col] = ps;
    ws[WS_NEGHP + seg * H + col] = ns;
  }
}

// ---- K2: blocks 0..63 = vecmat (reduce xsum + outraw partials); 64..1087 = GEMM
// GEMM: 128x128 tile, BK=32, double-buffered LDS with counted vmcnt (T3+T4),
// XOR bank-swizzle via pre-swizzled global source (T2, rule #21), setprio (T5).
__global__ __launch_bounds__(256) void gemm_vm_kernel(const u16* __restrict__ Xb,
                                                      const u16* __restrict__ Wbt,
                                                      const float* __restrict__ meta,
                                                      const float* __restrict__ W,
                                                      float* __restrict__ ws,
                                                      float* __restrict__ out) {
  __shared__ __align__(16) u16 lA[2][128 * 32];  // 2 x 8 KB: [m][k], linear dest
  __shared__ __align__(16) u16 lB[2][128 * 32];  // 2 x 8 KB: [n][k]
  __shared__ float xs[64];

  const int b = blockIdx.x, tid = threadIdx.x;

  if (b < 64) {
    // --- vecmat: out_raw[j] = (1/B) * sum_k xsum[k] * W[k][j] over k-chunk ---
    const int jx = b & 3, ky = b >> 2;
    if (tid < 64) {
      float s = 0.f;
      const float* p = &ws[WS_XSUMP + ky * 64 + tid];
#pragma unroll 8
      for (int q = 0; q < 256; ++q) s += p[q * H];
      xs[tid] = s;
      if (jx == 0) ws[WS_XSUM + ky * 64 + tid] = s;
    }
    __syncthreads();
    const int j = jx * 256 + tid;
    float s = 0.f;
#pragma unroll 8
    for (int k = 0; k < 64; ++k) s += xs[k] * W[(size_t)(ky * 64 + k) * H + j];
    ws[WS_ORAWP + ky * H + j] = s * (1.0f / (float)BATCH);
    return;
  }

  const int bg = b - 64;
  const int mt = bg & 127, nt = bg >> 7;
  const size_t row0 = (size_t)mt * 128;
  const int col0 = nt * 128;
  const int wave = tid >> 6;
  const int lane = tid & 63;
  const int quad = lane >> 4;
  const int l16 = lane & 15;
  const int wm = wave >> 1, wn = wave & 1;

  // staging: lane -> (row sr, 16B slot p) of a 16-row group; LDS dest stays
  // linear (global_load_lds writes base+lane*16); global k-chunk is XOR-swizzled
  // so slot p of row r holds chunk p ^ ((r>>1)&3)  (involution).
  const int sr = lane >> 2;
  const int sk = (((lane & 3) ^ ((sr >> 1) & 3)) * 8);
  // read side: same involution -> every aligned 8-lane group of ds_read_b128
  // covers all 8 bank-groups (conflict-free).
  const int ksw = ((quad ^ ((l16 >> 1) & 3)) * 8);

  f32x4 acc[4][4];
#pragma unroll
  for (int i = 0; i < 4; ++i)
#pragma unroll
    for (int j = 0; j < 4; ++j) acc[i][j] = (f32x4){0.f, 0.f, 0.f, 0.f};

  // prologue: stage tile 0 into buffer 0
#pragma unroll
  for (int i = 0; i < 2; ++i) {
    const int rg = i * 64 + wave * 16;  // wave-uniform row group
    const u16* ga = &Xb[(row0 + rg + sr) * H + 0 + sk];
    const u16* gb = &Wbt[(size_t)(col0 + rg + sr) * H + 0 + sk];
    __builtin_amdgcn_global_load_lds((glob_uint*)ga, (lds_uint*)&lA[0][rg * 32], 16, 0, 0);
    __builtin_amdgcn_global_load_lds((glob_uint*)gb, (lds_uint*)&lB[0][rg * 32], 16, 0, 0);
  }

  for (int kt = 0; kt < 32; ++kt) {
    const int cur = kt & 1;
    if (kt < 31) {
      // issue next tile's 4 loads into the other buffer (stay in flight across barrier)
      const int k0n = (kt + 1) * 32;
#pragma unroll
      for (int i = 0; i < 2; ++i) {
        const int rg = i * 64 + wave * 16;
        const u16* ga = &Xb[(row0 + rg + sr) * H + k0n + sk];
        const u16* gb = &Wbt[(size_t)(col0 + rg + sr) * H + k0n + sk];
        __builtin_amdgcn_global_load_lds((glob_uint*)ga, (lds_uint*)&lA[cur ^ 1][rg * 32], 16, 0, 0);
        __builtin_amdgcn_global_load_lds((glob_uint*)gb, (lds_uint*)&lB[cur ^ 1][rg * 32], 16, 0, 0);
      }
      // counted wait: 4 newest (tile kt+1) stay outstanding; tile kt's 4 are done
      asm volatile("s_waitcnt vmcnt(4)" ::: "memory");
    } else {
      asm volatile("s_waitcnt vmcnt(0)" ::: "memory");
    }
    asm volatile("s_barrier" ::: "memory");  // all waves' tile-kt staging landed

    bf16x8 av[4], bv[4];
#pragma unroll
    for (int f = 0; f < 4; ++f) {
      av[f] = __builtin_bit_cast(bf16x8, *(const u16x8*)&lA[cur][(wm * 64 + f * 16 + l16) * 32 + ksw]);
      bv[f] = __builtin_bit_cast(bf16x8, *(const u16x8*)&lB[cur][(wn * 64 + f * 16 + l16) * 32 + ksw]);
    }
    __builtin_amdgcn_s_setprio(1);
#pragma unroll
    for (int fm = 0; fm < 4; ++fm)
#pragma unroll
      for (int fn = 0; fn < 4; ++fn)
        acc[fm][fn] = __builtin_amdgcn_mfma_f32_16x16x32_bf16(av[fm], bv[fn], acc[fm][fn], 0, 0, 0);
    __builtin_amdgcn_s_setprio(0);
    // reads of lA/lB[cur] are complete (lgkmcnt drained by MFMA deps); fence + barrier
    // before next iteration's stage overwrites this buffer.
    asm volatile("s_waitcnt lgkmcnt(0)" ::: "memory");
    asm volatile("s_barrier" ::: "memory");
  }

  float mcol[4];
#pragma unroll
  for (int fn = 0; fn < 4; ++fn) mcol[fn] = meta[col0 + wn * 64 + fn * 16 + l16];
#pragma unroll
  for (int fm = 0; fm < 4; ++fm) {
#pragma unroll
    for (int fn = 0; fn < 4; ++fn) {
      int col = col0 + wn * 64 + fn * 16 + l16;
#pragma unroll
      for (int r = 0; r < 4; ++r) {
        size_t row = row0 + wm * 64 + fm * 16 + quad * 4 + r;
        out[row * H + col] = acc[fm][fn][r] * mcol[fn];
      }
    }
  }
}

// ---- K3: tail = finalize + new_w fused. 1024 blocks, one W-row each.
// Every block redundantly recomputes the global scalars from the small
// partial arrays (all L2/L3-resident) -> identical fp32 results, no dispatch.
__global__ __launch_bounds__(256) void tail_kernel(const float* __restrict__ W,
                                                   const float* __restrict__ meta,
                                                   const float* __restrict__ act,
                                                   const int* __restrict__ ptr,
                                                   const float* __restrict__ targ,
                                                   const float* __restrict__ homeo,
                                                   const float* __restrict__ mlr,
                                                   const float* __restrict__ win,
                                                   const float* __restrict__ dec,
                                                   const float* __restrict__ ws,
                                                   float* __restrict__ out_w,
                                                   float* __restrict__ meta_out,
                                                   float* __restrict__ hist_out) {
  __shared__ float r1[4], r2[4];
  const int r = blockIdx.x;        // W row
  const int t = threadIdx.x;
  const int c4 = t * 4;

  // --- per-thread: reduce oraw partials for 4 columns, compute om ---
  f32x4 oraw = (f32x4){0.f, 0.f, 0.f, 0.f};
#pragma unroll
  for (int i = 0; i < 16; ++i) {
    const float4 v = *(const float4*)&ws[WS_ORAWP + i * H + c4];
    oraw[0] += v.x; oraw[1] += v.y; oraw[2] += v.z; oraw[3] += v.w;
  }
  const float4 mv = *(const float4*)&meta[c4];
  f32x4 om;
  om[0] = mv.x * oraw[0]; om[1] = mv.y * oraw[1];
  om[2] = mv.z * oraw[2]; om[3] = mv.w * oraw[3];

  // --- global sums: sum(om), sum(act) ---
  float s1 = om[0] + om[1] + om[2] + om[3];
  float s2 = 0.f;
#pragma unroll
  for (int j = 0; j < 4; ++j) {
    int idx = t + j * 256;
    if (idx < 1000) s2 += act[idx];
  }
#pragma unroll
  for (int o = 32; o > 0; o >>= 1) {
    s1 += __shfl_down(s1, o, 64);
    s2 += __shfl_down(s2, o, 64);
  }
  if ((t & 63) == 0) { r1[t >> 6] = s1; r2[t >> 6] = s2; }
  __syncthreads();
  const float ts1 = r1[0] + r1[1] + r1[2] + r1[3];
  const float ts2 = r2[0] + r2[1] + r2[2] + r2[3];
  const float total_mean = ts1 / (float)H;
  const int p = ptr[0];
  const float hist_mean = (ts2 - act[p] + total_mean) / 1000.f;
  const float scale = 1.f + homeo[0] * (targ[0] - hist_mean);
  const float w99 = 0.01f * expf(-win[0] * dec[0]);

  // --- row scalars (wave-uniform loads) ---
  float oraw_r = 0.f;
#pragma unroll
  for (int i = 0; i < 16; ++i) oraw_r += ws[WS_ORAWP + i * H + r];
  const float om_r = meta[r] * oraw_r;
  float negh_r = 0.f;
#pragma unroll
  for (int i = 0; i < 5; ++i) negh_r += ws[WS_NEGHP + i * H + r];
  const float neg_r = negh_r + w99 * om_r;

  // --- per-thread column vectors: posv, xsum ---
  f32x4 pv = (f32x4){0.f, 0.f, 0.f, 0.f};
#pragma unroll
  for (int i = 0; i < 5; ++i) {
    const float4 v = *(const float4*)&ws[WS_POSVP + i * H + c4];
    pv[0] += v.x; pv[1] += v.y; pv[2] += v.z; pv[3] += v.w;
  }
  const float4 xv = *(const float4*)&ws[WS_XSUM + c4];
  float xx[4] = {xv.x, xv.y, xv.z, xv.w};
  const float4 wv = *(const float4*)&W[(size_t)r * H + c4];
  float wx[4] = {wv.x, wv.y, wv.z, wv.w};
  float4 o;
  float ox[4];
#pragma unroll
  for (int i = 0; i < 4; ++i) {
    float v = wx[i] + om_r * pv[i] - neg_r * (xx[i] * (1.0f / (float)BATCH));
    v = fminf(fmaxf(v, -1.f), 1.f);
    v = v * scale;
    ox[i] = fminf(fmaxf(v, -1.f), 1.f);
  }
  o.x = ox[0]; o.y = ox[1]; o.z = ox[2]; o.w = ox[3];
  *(float4*)&out_w[(size_t)r * H + c4] = o;

  // --- block 0: meta_out + hist_out ---
  if (r == 0) {
    float4 nm;
    float nx[4] = {mv.x, mv.y, mv.z, mv.w};
    float nr[4];
#pragma unroll
    for (int i = 0; i < 4; ++i) {
      float v = nx[i] + mlr[0] * (om[i] - nx[i]);
      nr[i] = fminf(fmaxf(v, 0.f), 2.f);
    }
    nm.x = nr[0]; nm.y = nr[1]; nm.z = nr[2]; nm.w = nr[3];
    *(float4*)&meta_out[c4] = nm;
#pragma unroll
    for (int j = 0; j < 4; ++j) {
      int idx = t + j * 256;
      if (idx < 1000) hist_out[idx] = (idx == p) ? total_mean : act[idx];
    }
  }
}

// ================= LEGACY FALLBACK (small ws) =================
__global__ __launch_bounds__(256) void colsum_kernel(const float* __restrict__ x,
                                                     float* __restrict__ xsum) {
  int col = blockIdx.x * 256 + threadIdx.x;
  size_t r0 = (size_t)blockIdx.y * 256;
  float s = 0.f;
#pragma unroll 8
  for (int r = 0; r < 256; ++r) s += x[(r0 + r) * H + col];
  atomicAdd(&xsum[col], s);
}

__global__ __launch_bounds__(256) void gemm_fallback_kernel(const float* __restrict__ X,
                                                            const float* __restrict__ W,
                                                            const float* __restrict__ meta,
                                                            float* __restrict__ out) {
  __shared__ __align__(16) u16 lA[128][40];
  __shared__ __align__(16) u16 lB[128][40];
  const int tid = threadIdx.x;
  const int wave = tid >> 6;
  const int lane = tid & 63;
  const int quad = lane >> 4;
  const int l16 = lane & 15;
  const int wm = wave >> 1, wn = wave & 1;
  const size_t row0 = (size_t)blockIdx.x * 128;
  const int col0 = blockIdx.y * 128;
  f32x4 acc[4][4];
#pragma unroll
  for (int i = 0; i < 4; ++i)
#pragma unroll
    for (int j = 0; j < 4; ++j) acc[i][j] = (f32x4){0.f, 0.f, 0.f, 0.f};
  for (int k0 = 0; k0 < H; k0 += 32) {
#pragma unroll
    for (int i = 0; i < 4; ++i) {
      int idx = i * 256 + tid;
      int r = idx >> 3, c4 = idx & 7;
      const float4 v = *(const float4*)&X[(row0 + r) * H + k0 + c4 * 4];
      ushort4 h;
      h.x = f2bf(v.x); h.y = f2bf(v.y); h.z = f2bf(v.z); h.w = f2bf(v.w);
      *(ushort4*)&lA[r][c4 * 4] = h;
    }
#pragma unroll
    for (int i = 0; i < 4; ++i) {
      int idx = i * 256 + tid;
      int kk = idx >> 5, c4 = idx & 31;
      const float4 v = *(const float4*)&W[(size_t)(k0 + kk) * H + col0 + c4 * 4];
      lB[c4 * 4 + 0][kk] = f2bf(v.x);
      lB[c4 * 4 + 1][kk] = f2bf(v.y);
      lB[c4 * 4 + 2][kk] = f2bf(v.z);
      lB[c4 * 4 + 3][kk] = f2bf(v.w);
    }
    __syncthreads();
    bf16x8 av[4], bv[4];
#pragma unroll
    for (int f = 0; f < 4; ++f) {
      av[f] = __builtin_bit_cast(bf16x8, *(const u16x8*)&lA[wm * 64 + f * 16 + l16][quad * 8]);
      bv[f] = __builtin_bit_cast(bf16x8, *(const u16x8*)&lB[wn * 64 + f * 16 + l16][quad * 8]);
    }
#pragma unroll
    for (int fm = 0; fm < 4; ++fm)
#pragma unroll
      for (int fn = 0; fn < 4; ++fn)
        acc[fm][fn] = __builtin_amdgcn_mfma_f32_16x16x32_bf16(av[fm], bv[fn], acc[fm][fn], 0, 0, 0);
    __syncthreads();
  }
  float mcol[4];
#pragma unroll
  for (int fn = 0; fn < 4; ++fn) mcol[fn] = meta[col0 + wn * 64 + fn * 16 + l16];
#pragma unroll
  for (int fm = 0; fm < 4; ++fm) {
#pragma unroll
    for (int fn = 0; fn < 4; ++fn) {
      int col = col0 + wn * 64 + fn * 16 + l16;
#pragma unroll
      for (int r = 0; r < 4; ++r) {
        size_t row = row0 + wm * 64 + fm * 16 + quad * 4 + r;
        out[row * H + col] = acc[fm][fn][r] * mcol[fn];
      }
    }
  }
}

__global__ __launch_bounds__(256) void vecmat_kernel(const float* __restrict__ W,
                                                     const float* __restrict__ xsum,
                                                     float* __restrict__ outraw) {
  int j = blockIdx.x * 256 + threadIdx.x;
  int k0 = blockIdx.y * 64;
  float s = 0.f;
#pragma unroll 8
  for (int k = 0; k < 64; ++k) s += xsum[k0 + k] * W[(size_t)(k0 + k) * H + j];
  atomicAdd(&outraw[j], s * (1.0f / (float)BATCH));
}

__global__ __launch_bounds__(256) void stdpvec_kernel(const float* __restrict__ pre,
                                                      const float* __restrict__ post,
                                                      const float* __restrict__ win,
                                                      const float* __restrict__ dec,
                                                      float* __restrict__ posv,
                                                      float* __restrict__ negh) {
  int col = blockIdx.x * 256 + threadIdx.x;
  int t0 = 1 + blockIdx.y * 20;
  float wd = win[0] * dec[0];
  float ps = 0.f, ns = 0.f;
  int tend = t0 + 20;
  if (tend > 100) tend = 100;
  for (int t = t0; t < tend; ++t) {
    float w = 0.01f * expf(-(float)(101 - t) * wd);
    ps += w * pre[t * H + col];
    if (t >= 2) ns += w * post[t * H + col];
  }
  atomicAdd(&posv[col], ps);
  atomicAdd(&negh[col], ns);
}

__global__ __launch_bounds__(1024) void finalize_kernel(const float* __restrict__ meta,
                                                        const float* __restrict__ act,
                                                        const int* __restrict__ ptr,
                                                        const float* __restrict__ targ,
                                                        const float* __restrict__ homeo,
                                                        const float* __restrict__ mlr,
                                                        const float* __restrict__ outraw,
                                                        float* __restrict__ outmean,
                                                        float* __restrict__ scalep,
                                                        float* __restrict__ meta_out,
                                                        float* __restrict__ hist_out) {
  __shared__ float r1[16], r2[16];
  __shared__ float sc[2];
  int t = threadIdx.x;
  float om = meta[t] * outraw[t];
  outmean[t] = om;
  float a = (t < 1000) ? act[t] : 0.f;
  float s1 = om, s2 = a;
#pragma unroll
  for (int o = 32; o > 0; o >>= 1) {
    s1 += __shfl_down(s1, o, 64);
    s2 += __shfl_down(s2, o, 64);
  }
  if ((t & 63) == 0) { r1[t >> 6] = s1; r2[t >> 6] = s2; }
  __syncthreads();
  if (t == 0) {
    float ts1 = 0.f, ts2 = 0.f;
#pragma unroll
    for (int i = 0; i < 16; ++i) { ts1 += r1[i]; ts2 += r2[i]; }
    float total_mean = ts1 / (float)H;
    int p = ptr[0];
    float hist_mean = (ts2 - act[p] + total_mean) / 1000.f;
    float diff = targ[0] - hist_mean;
    sc[0] = 1.f + homeo[0] * diff;
    sc[1] = total_mean;
    scalep[0] = sc[0];
  }
  __syncthreads();
  float nm = meta[t] + mlr[0] * (om - meta[t]);
  nm = fminf(fmaxf(nm, 0.f), 2.f);
  meta_out[t] = nm;
  if (t < 1000) hist_out[t] = (t == ptr[0]) ? sc[1] : act[t];
}

__global__ __launch_bounds__(256) void neww_kernel(const float* __restrict__ W,
                                                   const float* __restrict__ outmean,
                                                   const float* __restrict__ posv,
                                                   const float* __restrict__ negh,
                                                   const float* __restrict__ xsum,
                                                   const float* __restrict__ scalep,
                                                   const float* __restrict__ win,
                                                   const float* __restrict__ dec,
                                                   float* __restrict__ out) {
  int idx4 = blockIdx.x * 256 + threadIdx.x;
  int rr = idx4 >> 8;
  int c4 = (idx4 & 255) * 4;
  float w99 = 0.01f * expf(-win[0] * dec[0]);
  float scale = scalep[0];
  float om_r = outmean[rr];
  float neg_r = negh[rr] + w99 * om_r;
  const float4 wv = *(const float4*)&W[(size_t)rr * H + c4];
  const float4 pv = *(const float4*)&posv[c4];
  const float4 xv = *(const float4*)&xsum[c4];
  float4 o;
  float vx[4] = {wv.x, wv.y, wv.z, wv.w};
  float px[4] = {pv.x, pv.y, pv.z, pv.w};
  float xx[4] = {xv.x, xv.y, xv.z, xv.w};
  float ox[4];
#pragma unroll
  for (int i = 0; i < 4; ++i) {
    float v = vx[i] + om_r * px[i] - neg_r * (xx[i] * (1.0f / (float)BATCH));
    v = fminf(fmaxf(v, -1.f), 1.f);
    v = v * scale;
    ox[i] = fminf(fmaxf(v, -1.f), 1.f);
  }
  o.x = ox[0]; o.y = ox[1]; o.z = ox[2]; o.w = ox[3];
  *(float4*)&out[(size_t)rr * H + c4] = o;
}

extern "C" void kernel_launch(void* const* d_in, const int* in_sizes, int n_in,
                              void* d_out, int out_size, void* d_ws, size_t ws_size,
                              hipStream_t stream) {
  const float* x     = (const float*)d_in[0];
  const float* W     = (const float*)d_in[1];
  const float* meta  = (const float*)d_in[2];
  const float* pre   = (const float*)d_in[3];
  const float* post  = (const float*)d_in[4];
  const float* act   = (const float*)d_in[5];
  const int*   ptr   = (const int*)d_in[6];
  const float* win   = (const float*)d_in[7];
  const float* dec   = (const float*)d_in[8];
  const float* targ  = (const float*)d_in[9];
  const float* homeo = (const float*)d_in[10];
  const float* mlr   = (const float*)d_in[11];

  float* out_y    = (float*)d_out;              // [B,H]
  float* out_w    = out_y + (size_t)BATCH * H;  // [H,H]
  float* out_meta = out_w + (size_t)H * H;      // [H]
  float* out_hist = out_meta + H;               // [1000]

  float* ws = (float*)d_ws;
  u16* Xb  = (u16*)(ws + WS_BF16);       // [B][H] bf16, 32 MB
  u16* Wbt = Xb + (size_t)BATCH * H;     // [H][H] bf16 transposed, 2 MB

  const size_t ws_need = (size_t)WS_BF16 * sizeof(float) +
                         ((size_t)BATCH * H + (size_t)H * H) * sizeof(u16);

  if (ws_size >= ws_need) {
    // fast path: 3 dispatches, no memset, no atomics
    prep_kernel<<<532, 256, 0, stream>>>(x, W, Xb, Wbt, ws, pre, post, win, dec);
    gemm_vm_kernel<<<1088, 256, 0, stream>>>(Xb, Wbt, meta, W, ws, out_y);
    tail_kernel<<<1024, 256, 0, stream>>>(W, meta, act, ptr, targ, homeo, mlr,
                                          win, dec, ws, out_w, out_meta, out_hist);
  } else {
    // legacy path (atomics, in-gemm conversion)
    float* xsum    = ws;
    float* outraw  = ws + 1024;
    float* outmean = ws + 2048;
    float* posv    = ws + 3072;
    float* negh    = ws + 4096;
    float* scalep  = ws + 5120;
    hipMemsetAsync(d_ws, 0, 6144 * sizeof(float), stream);
    colsum_kernel<<<dim3(4, 64), 256, 0, stream>>>(x, xsum);
    gemm_fallback_kernel<<<dim3(128, 8), 256, 0, stream>>>(x, W, meta, out_y);
    vecmat_kernel<<<dim3(4, 16), 256, 0, stream>>>(W, xsum, outraw);
    stdpvec_kernel<<<dim3(4, 5), 256, 0, stream>>>(pre, post, win, dec, posv, negh);
    finalize_kernel<<<1, 1024, 0, stream>>>(meta, act, ptr, targ, homeo, mlr,
                                            outraw, outmean, scalep, out_meta, out_hist);
    neww_kernel<<<1024, 256, 0, stream>>>(W, outmean, posv, negh, xsum, scalep, win, dec, out_w);
  }
}

// Round 2
// 202.651 us; speedup vs baseline: 1.0611x; 1.0551x over previous
//
#include <hip/hip_runtime.h>
#include <hip/hip_bf16.h>

#define H 1024
#define BATCH 16384

typedef unsigned short u16;
typedef u16 u16x8 __attribute__((ext_vector_type(8)));
typedef __bf16 bf16x8 __attribute__((ext_vector_type(8)));
typedef float f32x4 __attribute__((ext_vector_type(4)));

typedef __attribute__((address_space(3))) unsigned int lds_uint;
typedef __attribute__((address_space(1))) const unsigned int glob_uint;

__device__ __forceinline__ u16 f2bf(float f) {
  unsigned int u = __float_as_uint(f);
  u += 0x7fffu + ((u >> 16) & 1u);   // round-to-nearest-even
  return (u16)(u >> 16);
}

// ================= FAST PATH =================
// ws float offsets
#define WS_XSUMP   0                      // [256][1024] per-block col-sum partials
#define WS_XSUM    (WS_XSUMP + 256 * H)   // [1024] reduced col sums
#define WS_ORAWP   (WS_XSUM + H)          // [16][1024] vecmat partials (pre-scaled 1/B)
#define WS_POSVP   (WS_ORAWP + 16 * H)    // [5][1024]
#define WS_NEGHP   (WS_POSVP + 5 * H)     // [5][1024]
#define WS_SCRATCH (WS_NEGHP + 5 * H)     // unused spare
#define WS_BF16    (WS_SCRATCH + 16)      // Xb then Wbt (u16), 16B-aligned

// ---- K1: prep = convx (blocks 0..255) + convw (256..511) + stdp partials (512..531)
__global__ __launch_bounds__(256) void prep_kernel(const float* __restrict__ X,
                                                   const float* __restrict__ W,
                                                   u16* __restrict__ Xb,
                                                   u16* __restrict__ Wbt,
                                                   float* __restrict__ ws,
                                                   const float* __restrict__ pre,
                                                   const float* __restrict__ post,
                                                   const float* __restrict__ win,
                                                   const float* __restrict__ dec) {
  __shared__ __align__(16) u16 t[64][72];
  const int b = blockIdx.x, tid = threadIdx.x;
  if (b < 256) {
    // --- convert X fp32->bf16, per-block column partial sums (no atomics) ---
    size_t r0 = (size_t)b * 64;
    float s0 = 0.f, s1 = 0.f, s2 = 0.f, s3 = 0.f;
#pragma unroll 4
    for (int r = 0; r < 64; ++r) {
      size_t off = (r0 + r) * H + tid * 4;
      const float4 v = *(const float4*)&X[off];
      ushort4 h;
      h.x = f2bf(v.x); h.y = f2bf(v.y); h.z = f2bf(v.z); h.w = f2bf(v.w);
      *(ushort4*)&Xb[off] = h;
      s0 += v.x; s1 += v.y; s2 += v.z; s3 += v.w;
    }
    float* row = &ws[WS_XSUMP + b * H];
    row[tid * 4 + 0] = s0; row[tid * 4 + 1] = s1;
    row[tid * 4 + 2] = s2; row[tid * 4 + 3] = s3;
  } else if (b < 512) {
    // --- convert + transpose W -> Wbt bf16 [n][k] ---
    const int b2 = b - 256;
    const int n0 = (b2 & 15) * 64, k0 = (b2 >> 4) * 64;
    const int rb = tid >> 4, c4 = tid & 15;
#pragma unroll
    for (int i = 0; i < 4; ++i) {
      int r = rb + i * 16;
      const float4 v = *(const float4*)&W[(size_t)(k0 + r) * H + n0 + c4 * 4];
      t[c4 * 4 + 0][r] = f2bf(v.x);
      t[c4 * 4 + 1][r] = f2bf(v.y);
      t[c4 * 4 + 2][r] = f2bf(v.z);
      t[c4 * 4 + 3][r] = f2bf(v.w);
    }
    __syncthreads();
    const int seg = tid & 7;
#pragma unroll
    for (int p = 0; p < 2; ++p) {
      int wr = p * 32 + (tid >> 3);
      *(u16x8*)&Wbt[(size_t)(n0 + wr) * H + k0 + seg * 8] = *(const u16x8*)&t[wr][seg * 8];
    }
  } else {
    // --- STDP weighted history partials (no atomics) ---
    const int b2 = b - 512;               // 0..19
    const int col = (b2 & 3) * 256 + tid;
    const int seg = b2 >> 2;              // 0..4
    const int t0 = 1 + seg * 20;
    int tend = t0 + 20; if (tend > 100) tend = 100;
    float wd = win[0] * dec[0];
    float ps = 0.f, ns = 0.f;
    for (int tt = t0; tt < tend; ++tt) {
      float w = 0.01f * expf(-(float)(101 - tt) * wd);
      ps += w * pre[tt * H + col];
      if (tt >= 2) ns += w * post[tt * H + col];
    }
    ws[WS_POSVP + seg * H + col] = ps;
    ws[WS_NEGHP + seg * H + col] = ns;
  }
}

// ---- K2: blocks 0..63 = vecmat; 64..319 = GEMM (256x256 tile, BK=64, 8-phase T3+T4)
// 8 waves (2M x 4N), 512 threads, per-wave C = 128x64. LDS = 4-slot half-tile
// rings for A and B (2 K-tiles deep, 128 KB). Counted vmcnt(4) at phases 4/8 only.
// T2: linear LDS dest + XOR-swizzled global source (chunk ^= row&7), same XOR on read.
__global__ __launch_bounds__(512, 2) void gemm_vm_kernel(const u16* __restrict__ Xb,
                                                         const u16* __restrict__ Wbt,
                                                         const float* __restrict__ meta,
                                                         const float* __restrict__ W,
                                                         float* __restrict__ ws,
                                                         float* __restrict__ out) {
  // 128 KB: A ring u16[0,32768) = 4 slots x 16KB ; B ring u16[32768,65536)
  __shared__ __align__(16) u16 lds[65536];

  const int b = blockIdx.x, tid = threadIdx.x;

  if (b < 64) {
    // --- vecmat: out_raw[j] = (1/B) * sum_k xsum[k] * W[k][j] over k-chunk ---
    float* xs = (float*)lds;
    const int jx = b & 3, ky = b >> 2;
    if (tid < 64) {
      float s = 0.f;
      const float* p = &ws[WS_XSUMP + ky * 64 + tid];
#pragma unroll 8
      for (int q = 0; q < 256; ++q) s += p[q * H];
      xs[tid] = s;
      if (jx == 0) ws[WS_XSUM + ky * 64 + tid] = s;
    }
    __syncthreads();
    if (tid < 256) {
      const int j = jx * 256 + tid;
      float s = 0.f;
#pragma unroll 8
      for (int k = 0; k < 64; ++k) s += xs[k] * W[(size_t)(ky * 64 + k) * H + j];
      ws[WS_ORAWP + ky * H + j] = s * (1.0f / (float)BATCH);
    }
    return;
  }

  const int bg = b - 64;                 // 0..255
  const int mt = bg >> 2, nt = bg & 3;   // 64 x 4 tiles; same-mt blocks adjacent
  const size_t row0 = (size_t)mt * 256;
  const int col0 = nt * 256;
  const int wid = tid >> 6, lane = tid & 63;
  const int wm = wid >> 2, wn = wid & 3; // 2 M-waves x 4 N-waves
  const int quad = lane >> 4, l16 = lane & 15;
  const int xsw = l16 & 7;               // read-side row XOR

  // staging lane pattern: each instr writes 1KB linear LDS (8 rows x 128B);
  // global k-chunk pre-swizzled so LDS slot (r,c) holds chunk c ^ (r&7).
  const int srow = lane >> 3;                   // 0..7
  const int schunk = (lane & 7) ^ (srow & 7);   // pre-swizzled source chunk

  auto stageA = [&](int t, int h) {
#pragma unroll
    for (int s = 0; s < 2; ++s) {
      const u16* ga = &Xb[(row0 + h * 128 + s * 64 + wid * 8 + srow) * H + t * 64 + schunk * 8];
      lds_uint* ld = (lds_uint*)&lds[(((2 * t + h) & 3) * 8192) + s * 4096 + wid * 512];
      __builtin_amdgcn_global_load_lds((glob_uint*)ga, ld, 16, 0, 0);
    }
  };
  auto stageB = [&](int t, int h) {
#pragma unroll
    for (int s = 0; s < 2; ++s) {
      const u16* gb = &Wbt[(size_t)(col0 + h * 128 + s * 64 + wid * 8 + srow) * H + t * 64 + schunk * 8];
      lds_uint* ld = (lds_uint*)&lds[32768 + (((2 * t + h) & 3) * 8192) + s * 4096 + wid * 512];
      __builtin_amdgcn_global_load_lds((glob_uint*)gb, ld, 16, 0, 0);
    }
  };

  f32x4 acc[8][4];
#pragma unroll
  for (int i = 0; i < 8; ++i)
#pragma unroll
    for (int j = 0; j < 4; ++j) acc[i][j] = (f32x4){0.f, 0.f, 0.f, 0.f};

  // prologue: A(t0) both halves, B(t0), B(t1); first 8 instrs must land
  stageA(0, 0); stageA(0, 1); stageB(0, 0); stageB(0, 1); stageB(1, 0); stageB(1, 1);
  asm volatile("s_waitcnt vmcnt(4)" ::: "memory");
  __builtin_amdgcn_s_barrier();

  for (int it = 0; it < 8; ++it) {
    const bool last = (it == 7);
#pragma unroll
    for (int hf = 0; hf < 2; ++hf) {
      const int tc = 2 * it + hf;                              // tile being computed
      const int aslot = ((2 * tc + wm) & 3) * 8192;            // this wave's A half
      const int bslot = 32768 + ((2 * tc + (wn >> 1)) & 3) * 8192;
      const int brl = (wn & 1) * 64;
      bf16x8 bv[4][2];                                         // tile's B frags (read once)
#pragma unroll
      for (int sub = 0; sub < 4; ++sub) {
        // ---- stage issue: one half-tile per phase (ring schedule) ----
        if (hf == 0) {
          if (sub == 0)      stageA(2 * it + 1, 0);
          else if (sub == 1) stageA(2 * it + 1, 1);
          else if (sub == 2) { if (!last) stageB(2 * it + 2, 0); }
          else               { if (!last) stageB(2 * it + 2, 1); }
        } else {
          if (sub == 0)      { if (!last) stageA(2 * it + 2, 0); }
          else if (sub == 1) { if (!last) stageA(2 * it + 2, 1); }
          else if (sub == 2) { if (!last) stageB(2 * it + 3, 0); }
          else               { if (!last) stageB(2 * it + 3, 1); }
        }
        // ---- ds reads for this phase's fragments ----
        if (sub == 0) {
#pragma unroll
          for (int fn = 0; fn < 4; ++fn)
#pragma unroll
            for (int ks = 0; ks < 2; ++ks)
              bv[fn][ks] = __builtin_bit_cast(bf16x8,
                *(const u16x8*)&lds[bslot + (brl + fn * 16 + l16) * 64 + (((ks * 4 + quad) ^ xsw) * 8)]);
        }
        bf16x8 av[2][2];
#pragma unroll
        for (int fi = 0; fi < 2; ++fi)
#pragma unroll
          for (int ks = 0; ks < 2; ++ks)
            av[fi][ks] = __builtin_bit_cast(bf16x8,
              *(const u16x8*)&lds[aslot + ((sub * 2 + fi) * 16 + l16) * 64 + (((ks * 4 + quad) ^ xsw) * 8)]);

        __builtin_amdgcn_s_barrier();
        asm volatile("s_waitcnt lgkmcnt(0)" ::: "memory");
        __builtin_amdgcn_sched_barrier(0);   // rule #18: pin MFMA after the drain
        __builtin_amdgcn_s_setprio(1);
#pragma unroll
        for (int fi = 0; fi < 2; ++fi)
#pragma unroll
          for (int fn = 0; fn < 4; ++fn)
#pragma unroll
            for (int ks = 0; ks < 2; ++ks)
              acc[sub * 2 + fi][fn] = __builtin_amdgcn_mfma_f32_16x16x32_bf16(
                  av[fi][ks], bv[fn][ks], acc[sub * 2 + fi][fn], 0, 0, 0);
        __builtin_amdgcn_s_setprio(0);
        // ---- counted vmcnt once per K-tile, before the phase-end barrier ----
        if (sub == 3) {
          if (hf == 0 && last) asm volatile("s_waitcnt vmcnt(0)" ::: "memory");
          else                 asm volatile("s_waitcnt vmcnt(4)" ::: "memory");
        }
        __builtin_amdgcn_s_barrier();
      }
    }
  }

  // ---- epilogue: scale by meta and store ----
  float mcol[4];
#pragma unroll
  for (int fn = 0; fn < 4; ++fn) mcol[fn] = meta[col0 + wn * 64 + fn * 16 + l16];
#pragma unroll
  for (int fm = 0; fm < 8; ++fm) {
#pragma unroll
    for (int fn = 0; fn < 4; ++fn) {
      const int col = col0 + wn * 64 + fn * 16 + l16;
#pragma unroll
      for (int r = 0; r < 4; ++r) {
        size_t row = row0 + wm * 128 + fm * 16 + quad * 4 + r;
        out[row * H + col] = acc[fm][fn][r] * mcol[fn];
      }
    }
  }
}

// ---- K3: tail = finalize + new_w fused. 1024 blocks, one W-row each.
__global__ __launch_bounds__(256) void tail_kernel(const float* __restrict__ W,
                                                   const float* __restrict__ meta,
                                                   const float* __restrict__ act,
                                                   const int* __restrict__ ptr,
                                                   const float* __restrict__ targ,
                                                   const float* __restrict__ homeo,
                                                   const float* __restrict__ mlr,
                                                   const float* __restrict__ win,
                                                   const float* __restrict__ dec,
                                                   const float* __restrict__ ws,
                                                   float* __restrict__ out_w,
                                                   float* __restrict__ meta_out,
                                                   float* __restrict__ hist_out) {
  __shared__ float r1[4], r2[4];
  const int r = blockIdx.x;        // W row
  const int t = threadIdx.x;
  const int c4 = t * 4;

  // --- per-thread: reduce oraw partials for 4 columns, compute om ---
  f32x4 oraw = (f32x4){0.f, 0.f, 0.f, 0.f};
#pragma unroll
  for (int i = 0; i < 16; ++i) {
    const float4 v = *(const float4*)&ws[WS_ORAWP + i * H + c4];
    oraw[0] += v.x; oraw[1] += v.y; oraw[2] += v.z; oraw[3] += v.w;
  }
  const float4 mv = *(const float4*)&meta[c4];
  f32x4 om;
  om[0] = mv.x * oraw[0]; om[1] = mv.y * oraw[1];
  om[2] = mv.z * oraw[2]; om[3] = mv.w * oraw[3];

  // --- global sums: sum(om), sum(act) ---
  float s1 = om[0] + om[1] + om[2] + om[3];
  float s2 = 0.f;
#pragma unroll
  for (int j = 0; j < 4; ++j) {
    int idx = t + j * 256;
    if (idx < 1000) s2 += act[idx];
  }
#pragma unroll
  for (int o = 32; o > 0; o >>= 1) {
    s1 += __shfl_down(s1, o, 64);
    s2 += __shfl_down(s2, o, 64);
  }
  if ((t & 63) == 0) { r1[t >> 6] = s1; r2[t >> 6] = s2; }
  __syncthreads();
  const float ts1 = r1[0] + r1[1] + r1[2] + r1[3];
  const float ts2 = r2[0] + r2[1] + r2[2] + r2[3];
  const float total_mean = ts1 / (float)H;
  const int p = ptr[0];
  const float hist_mean = (ts2 - act[p] + total_mean) / 1000.f;
  const float scale = 1.f + homeo[0] * (targ[0] - hist_mean);
  const float w99 = 0.01f * expf(-win[0] * dec[0]);

  // --- row scalars (wave-uniform loads) ---
  float oraw_r = 0.f;
#pragma unroll
  for (int i = 0; i < 16; ++i) oraw_r += ws[WS_ORAWP + i * H + r];
  const float om_r = meta[r] * oraw_r;
  float negh_r = 0.f;
#pragma unroll
  for (int i = 0; i < 5; ++i) negh_r += ws[WS_NEGHP + i * H + r];
  const float neg_r = negh_r + w99 * om_r;

  // --- per-thread column vectors: posv, xsum ---
  f32x4 pv = (f32x4){0.f, 0.f, 0.f, 0.f};
#pragma unroll
  for (int i = 0; i < 5; ++i) {
    const float4 v = *(const float4*)&ws[WS_POSVP + i * H + c4];
    pv[0] += v.x; pv[1] += v.y; pv[2] += v.z; pv[3] += v.w;
  }
  const float4 xv = *(const float4*)&ws[WS_XSUM + c4];
  float xx[4] = {xv.x, xv.y, xv.z, xv.w};
  const float4 wv = *(const float4*)&W[(size_t)r * H + c4];
  float wx[4] = {wv.x, wv.y, wv.z, wv.w};
  float4 o;
  float ox[4];
#pragma unroll
  for (int i = 0; i < 4; ++i) {
    float v = wx[i] + om_r * pv[i] - neg_r * (xx[i] * (1.0f / (float)BATCH));
    v = fminf(fmaxf(v, -1.f), 1.f);
    v = v * scale;
    ox[i] = fminf(fmaxf(v, -1.f), 1.f);
  }
  o.x = ox[0]; o.y = ox[1]; o.z = ox[2]; o.w = ox[3];
  *(float4*)&out_w[(size_t)r * H + c4] = o;

  // --- block 0: meta_out + hist_out ---
  if (r == 0) {
    float4 nm;
    float nx[4] = {mv.x, mv.y, mv.z, mv.w};
    float nr[4];
#pragma unroll
    for (int i = 0; i < 4; ++i) {
      float v = nx[i] + mlr[0] * (om[i] - nx[i]);
      nr[i] = fminf(fmaxf(v, 0.f), 2.f);
    }
    nm.x = nr[0]; nm.y = nr[1]; nm.z = nr[2]; nm.w = nr[3];
    *(float4*)&meta_out[c4] = nm;
#pragma unroll
    for (int j = 0; j < 4; ++j) {
      int idx = t + j * 256;
      if (idx < 1000) hist_out[idx] = (idx == p) ? total_mean : act[idx];
    }
  }
}

// ================= LEGACY FALLBACK (small ws) =================
__global__ __launch_bounds__(256) void colsum_kernel(const float* __restrict__ x,
                                                     float* __restrict__ xsum) {
  int col = blockIdx.x * 256 + threadIdx.x;
  size_t r0 = (size_t)blockIdx.y * 256;
  float s = 0.f;
#pragma unroll 8
  for (int r = 0; r < 256; ++r) s += x[(r0 + r) * H + col];
  atomicAdd(&xsum[col], s);
}

__global__ __launch_bounds__(256) void gemm_fallback_kernel(const float* __restrict__ X,
                                                            const float* __restrict__ W,
                                                            const float* __restrict__ meta,
                                                            float* __restrict__ out) {
  __shared__ __align__(16) u16 lA[128][40];
  __shared__ __align__(16) u16 lB[128][40];
  const int tid = threadIdx.x;
  const int wave = tid >> 6;
  const int lane = tid & 63;
  const int quad = lane >> 4;
  const int l16 = lane & 15;
  const int wm = wave >> 1, wn = wave & 1;
  const size_t row0 = (size_t)blockIdx.x * 128;
  const int col0 = blockIdx.y * 128;
  f32x4 acc[4][4];
#pragma unroll
  for (int i = 0; i < 4; ++i)
#pragma unroll
    for (int j = 0; j < 4; ++j) acc[i][j] = (f32x4){0.f, 0.f, 0.f, 0.f};
  for (int k0 = 0; k0 < H; k0 += 32) {
#pragma unroll
    for (int i = 0; i < 4; ++i) {
      int idx = i * 256 + tid;
      int r = idx >> 3, c4 = idx & 7;
      const float4 v = *(const float4*)&X[(row0 + r) * H + k0 + c4 * 4];
      ushort4 h;
      h.x = f2bf(v.x); h.y = f2bf(v.y); h.z = f2bf(v.z); h.w = f2bf(v.w);
      *(ushort4*)&lA[r][c4 * 4] = h;
    }
#pragma unroll
    for (int i = 0; i < 4; ++i) {
      int idx = i * 256 + tid;
      int kk = idx >> 5, c4 = idx & 31;
      const float4 v = *(const float4*)&W[(size_t)(k0 + kk) * H + col0 + c4 * 4];
      lB[c4 * 4 + 0][kk] = f2bf(v.x);
      lB[c4 * 4 + 1][kk] = f2bf(v.y);
      lB[c4 * 4 + 2][kk] = f2bf(v.z);
      lB[c4 * 4 + 3][kk] = f2bf(v.w);
    }
    __syncthreads();
    bf16x8 av[4], bv[4];
#pragma unroll
    for (int f = 0; f < 4; ++f) {
      av[f] = __builtin_bit_cast(bf16x8, *(const u16x8*)&lA[wm * 64 + f * 16 + l16][quad * 8]);
      bv[f] = __builtin_bit_cast(bf16x8, *(const u16x8*)&lB[wn * 64 + f * 16 + l16][quad * 8]);
    }
#pragma unroll
    for (int fm = 0; fm < 4; ++fm)
#pragma unroll
      for (int fn = 0; fn < 4; ++fn)
        acc[fm][fn] = __builtin_amdgcn_mfma_f32_16x16x32_bf16(av[fm], bv[fn], acc[fm][fn], 0, 0, 0);
    __syncthreads();
  }
  float mcol[4];
#pragma unroll
  for (int fn = 0; fn < 4; ++fn) mcol[fn] = meta[col0 + wn * 64 + fn * 16 + l16];
#pragma unroll
  for (int fm = 0; fm < 4; ++fm) {
#pragma unroll
    for (int fn = 0; fn < 4; ++fn) {
      int col = col0 + wn * 64 + fn * 16 + l16;
#pragma unroll
      for (int r = 0; r < 4; ++r) {
        size_t row = row0 + wm * 64 + fm * 16 + quad * 4 + r;
        out[row * H + col] = acc[fm][fn][r] * mcol[fn];
      }
    }
  }
}

__global__ __launch_bounds__(256) void vecmat_kernel(const float* __restrict__ W,
                                                     const float* __restrict__ xsum,
                                                     float* __restrict__ outraw) {
  int j = blockIdx.x * 256 + threadIdx.x;
  int k0 = blockIdx.y * 64;
  float s = 0.f;
#pragma unroll 8
  for (int k = 0; k < 64; ++k) s += xsum[k0 + k] * W[(size_t)(k0 + k) * H + j];
  atomicAdd(&outraw[j], s * (1.0f / (float)BATCH));
}

__global__ __launch_bounds__(256) void stdpvec_kernel(const float* __restrict__ pre,
                                                      const float* __restrict__ post,
                                                      const float* __restrict__ win,
                                                      const float* __restrict__ dec,
                                                      float* __restrict__ posv,
                                                      float* __restrict__ negh) {
  int col = blockIdx.x * 256 + threadIdx.x;
  int t0 = 1 + blockIdx.y * 20;
  float wd = win[0] * dec[0];
  float ps = 0.f, ns = 0.f;
  int tend = t0 + 20;
  if (tend > 100) tend = 100;
  for (int t = t0; t < tend; ++t) {
    float w = 0.01f * expf(-(float)(101 - t) * wd);
    ps += w * pre[t * H + col];
    if (t >= 2) ns += w * post[t * H + col];
  }
  atomicAdd(&posv[col], ps);
  atomicAdd(&negh[col], ns);
}

__global__ __launch_bounds__(1024) void finalize_kernel(const float* __restrict__ meta,
                                                        const float* __restrict__ act,
                                                        const int* __restrict__ ptr,
                                                        const float* __restrict__ targ,
                                                        const float* __restrict__ homeo,
                                                        const float* __restrict__ mlr,
                                                        const float* __restrict__ outraw,
                                                        float* __restrict__ outmean,
                                                        float* __restrict__ scalep,
                                                        float* __restrict__ meta_out,
                                                        float* __restrict__ hist_out) {
  __shared__ float r1[16], r2[16];
  __shared__ float sc[2];
  int t = threadIdx.x;
  float om = meta[t] * outraw[t];
  outmean[t] = om;
  float a = (t < 1000) ? act[t] : 0.f;
  float s1 = om, s2 = a;
#pragma unroll
  for (int o = 32; o > 0; o >>= 1) {
    s1 += __shfl_down(s1, o, 64);
    s2 += __shfl_down(s2, o, 64);
  }
  if ((t & 63) == 0) { r1[t >> 6] = s1; r2[t >> 6] = s2; }
  __syncthreads();
  if (t == 0) {
    float ts1 = 0.f, ts2 = 0.f;
#pragma unroll
    for (int i = 0; i < 16; ++i) { ts1 += r1[i]; ts2 += r2[i]; }
    float total_mean = ts1 / (float)H;
    int p = ptr[0];
    float hist_mean = (ts2 - act[p] + total_mean) / 1000.f;
    float diff = targ[0] - hist_mean;
    sc[0] = 1.f + homeo[0] * diff;
    sc[1] = total_mean;
    scalep[0] = sc[0];
  }
  __syncthreads();
  float nm = meta[t] + mlr[0] * (om - meta[t]);
  nm = fminf(fmaxf(nm, 0.f), 2.f);
  meta_out[t] = nm;
  if (t < 1000) hist_out[t] = (t == ptr[0]) ? sc[1] : act[t];
}

__global__ __launch_bounds__(256) void neww_kernel(const float* __restrict__ W,
                                                   const float* __restrict__ outmean,
                                                   const float* __restrict__ posv,
                                                   const float* __restrict__ negh,
                                                   const float* __restrict__ xsum,
                                                   const float* __restrict__ scalep,
                                                   const float* __restrict__ win,
                                                   const float* __restrict__ dec,
                                                   float* __restrict__ out) {
  int idx4 = blockIdx.x * 256 + threadIdx.x;
  int rr = idx4 >> 8;
  int c4 = (idx4 & 255) * 4;
  float w99 = 0.01f * expf(-win[0] * dec[0]);
  float scale = scalep[0];
  float om_r = outmean[rr];
  float neg_r = negh[rr] + w99 * om_r;
  const float4 wv = *(const float4*)&W[(size_t)rr * H + c4];
  const float4 pv = *(const float4*)&posv[c4];
  const float4 xv = *(const float4*)&xsum[c4];
  float4 o;
  float vx[4] = {wv.x, wv.y, wv.z, wv.w};
  float px[4] = {pv.x, pv.y, pv.z, pv.w};
  float xx[4] = {xv.x, xv.y, xv.z, xv.w};
  float ox[4];
#pragma unroll
  for (int i = 0; i < 4; ++i) {
    float v = vx[i] + om_r * px[i] - neg_r * (xx[i] * (1.0f / (float)BATCH));
    v = fminf(fmaxf(v, -1.f), 1.f);
    v = v * scale;
    ox[i] = fminf(fmaxf(v, -1.f), 1.f);
  }
  o.x = ox[0]; o.y = ox[1]; o.z = ox[2]; o.w = ox[3];
  *(float4*)&out[(size_t)rr * H + c4] = o;
}

extern "C" void kernel_launch(void* const* d_in, const int* in_sizes, int n_in,
                              void* d_out, int out_size, void* d_ws, size_t ws_size,
                              hipStream_t stream) {
  const float* x     = (const float*)d_in[0];
  const float* W     = (const float*)d_in[1];
  const float* meta  = (const float*)d_in[2];
  const float* pre   = (const float*)d_in[3];
  const float* post  = (const float*)d_in[4];
  const float* act   = (const float*)d_in[5];
  const int*   ptr   = (const int*)d_in[6];
  const float* win   = (const float*)d_in[7];
  const float* dec   = (const float*)d_in[8];
  const float* targ  = (const float*)d_in[9];
  const float* homeo = (const float*)d_in[10];
  const float* mlr   = (const float*)d_in[11];

  float* out_y    = (float*)d_out;              // [B,H]
  float* out_w    = out_y + (size_t)BATCH * H;  // [H,H]
  float* out_meta = out_w + (size_t)H * H;      // [H]
  float* out_hist = out_meta + H;               // [1000]

  float* ws = (float*)d_ws;
  u16* Xb  = (u16*)(ws + WS_BF16);       // [B][H] bf16, 32 MB
  u16* Wbt = Xb + (size_t)BATCH * H;     // [H][H] bf16 transposed, 2 MB

  const size_t ws_need = (size_t)WS_BF16 * sizeof(float) +
                         ((size_t)BATCH * H + (size_t)H * H) * sizeof(u16);

  if (ws_size >= ws_need) {
    // fast path: 3 dispatches, no memset, no atomics
    prep_kernel<<<532, 256, 0, stream>>>(x, W, Xb, Wbt, ws, pre, post, win, dec);
    gemm_vm_kernel<<<320, 512, 0, stream>>>(Xb, Wbt, meta, W, ws, out_y);
    tail_kernel<<<1024, 256, 0, stream>>>(W, meta, act, ptr, targ, homeo, mlr,
                                          win, dec, ws, out_w, out_meta, out_hist);
  } else {
    // legacy path (atomics, in-gemm conversion)
    float* xsum    = ws;
    float* outraw  = ws + 1024;
    float* outmean = ws + 2048;
    float* posv    = ws + 3072;
    float* negh    = ws + 4096;
    float* scalep  = ws + 5120;
    hipMemsetAsync(d_ws, 0, 6144 * sizeof(float), stream);
    colsum_kernel<<<dim3(4, 64), 256, 0, stream>>>(x, xsum);
    gemm_fallback_kernel<<<dim3(128, 8), 256, 0, stream>>>(x, W, meta, out_y);
    vecmat_kernel<<<dim3(4, 16), 256, 0, stream>>>(W, xsum, outraw);
    stdpvec_kernel<<<dim3(4, 5), 256, 0, stream>>>(pre, post, win, dec, posv, negh);
    finalize_kernel<<<1, 1024, 0, stream>>>(meta, act, ptr, targ, homeo, mlr,
                                            outraw, outmean, scalep, out_meta, out_hist);
    neww_kernel<<<1024, 256, 0, stream>>>(W, outmean, posv, negh, xsum, scalep, win, dec, out_w);
  }
}